// Round 3
// baseline (721.540 us; speedup 1.0000x reference)
//
#include <hip/hip_runtime.h>
#include <hip/hip_bf16.h>

typedef __attribute__((ext_vector_type(4))) float f32x4;
typedef __attribute__((ext_vector_type(8))) short short8;

#define LDS_BUF 40960

// ---------- helpers ----------
static __device__ __forceinline__ unsigned short f2b(float f) {
    unsigned int x = __float_as_uint(f);
    return (unsigned short)((x + 0x7fffu + ((x >> 16) & 1u)) >> 16);
}
static __device__ __forceinline__ float sigm(float x) { return 1.0f / (1.0f + __expf(-x)); }
static __device__ __forceinline__ float tanh_fast(float x) { return 2.0f / (1.0f + __expf(-2.0f * x)) - 1.0f; }

static __device__ __forceinline__ void gload16(const void* g, void* l) {
    __builtin_amdgcn_global_load_lds((const __attribute__((address_space(1))) void*)g,
                                     (__attribute__((address_space(3))) void*)l, 16, 0, 0);
}

// ---------- convert inputs to bf16 workspace ----------
__global__ void convert_kernel(const float* __restrict__ feats, const float* __restrict__ Wx,
                               const float* __restrict__ Wh, const float* __restrict__ Wp,
                               unsigned short* __restrict__ fb, unsigned short* __restrict__ wcat,
                               int nf4, int nw4) {
    int idx = blockIdx.x * blockDim.x + threadIdx.x;
    int stride = gridDim.x * blockDim.x;
    int tot = nf4 + nw4;
    for (int i = idx; i < tot; i += stride) {
        float4 v;
        unsigned short* dst;
        if (i < nf4) {
            v = ((const float4*)feats)[i];
            dst = fb + (size_t)i * 4;
        } else {
            int t = i - nf4;
            int row = t >> 8;
            int c4 = (t & 255) * 4;
            const float* src = nullptr;
            if (row < 2560) {
                src = (c4 < 512) ? (Wx + (size_t)row * 512 + c4)
                                 : (Wh + (size_t)row * 512 + (c4 - 512));
            } else {
                if (c4 < 512) src = Wp + (size_t)(row - 2560) * 512 + c4;
            }
            if (src) v = *(const float4*)src;
            else     v = make_float4(0.f, 0.f, 0.f, 0.f);
            dst = wcat + (size_t)row * 1024 + c4;
        }
        ushort4 o;
        o.x = f2b(v.x); o.y = f2b(v.y); o.z = f2b(v.z); o.w = f2b(v.w);
        *(ushort4*)dst = o;
    }
}

// ---------- fused level kernel ----------
// Tile: 256 rows x (6 strips x 64 cols). K-step 32 (64B), TRIPLE-buffered LDS
// (3 x 40KB, 1 block/CU), counted vmcnt(5) pipeline (never drain in-loop),
// global_load_lds staging with pre-swizzled source, setprio around MFMA.
// 8 waves: wr=w>>1 (64-row group, 4 x mi16), wc=w&1 (32-col half, 2 x ni16).
__global__ __launch_bounds__(512, 2)
void level_kernel(const unsigned short* __restrict__ fb,    // [N,512] bf16
                  const unsigned short* __restrict__ wcat,  // [3072,1024] bf16
                  unsigned short* __restrict__ hb,          // [N,512] bf16
                  const float* __restrict__ bx, const float* __restrict__ bh,
                  const float* __restrict__ bp,
                  float* __restrict__ c_all,                // [N,512] f32
                  float* __restrict__ out,                  // [N,512] f32
                  int s, int e, int level, int nks) {
    __shared__ unsigned char sm[3 * LDS_BUF];

    const int tid = threadIdx.x;
    const int lane = tid & 63;
    const int w = tid >> 6;
    const int wr = w >> 1, wc = w & 1;
    const int q4 = lane >> 4;
    const int nbase = s + blockIdx.x * 256;
    const int j0 = blockIdx.y * 64;

    // ---- staging source offsets (bf16-element units); chunk id = i*512+tid
    unsigned aOff[2], hOff[2], bOff[3];
#pragma unroll
    for (int i = 0; i < 2; ++i) {
        int id = i * 512 + tid;
        int row = id >> 2, slot = id & 3;
        int sw = slot ^ ((row >> 1) & 3);         // pre-swizzled global slot
        int n = nbase + row; if (n > e - 1) n = e - 1;
        aOff[i] = (unsigned)n * 512u + sw * 8;
        int pr = (n - 1) >> 3; if (pr < 0) pr = 0;
        hOff[i] = (unsigned)pr * 512u + sw * 8;
    }
#pragma unroll
    for (int i = 0; i < 3; ++i) {
        int id = i * 512 + tid;
        int row = id >> 2, slot = id & 3;         // row 0..383 (6 strips x 64)
        int sw = slot ^ ((row >> 1) & 3);
        int wrow = (row >> 6) * 512 + j0 + (row & 63);
        bOff[i] = (unsigned)wrow * 1024u + sw * 8;
    }
    const unsigned ldsW = (unsigned)w * 1024u;    // wave-uniform segment base

    // ---- ds_read addresses (swizzled; constant across ks) ----
    const int f = (lane >> 1) & 3;
    const unsigned axor = (unsigned)((q4 ^ f) << 4);
    const unsigned aBase = (unsigned)((wr * 64 + (lane & 15)) * 64) + axor;
    const unsigned bBase = 16384u + (unsigned)((wc * 32 + (lane & 15)) * 64) + axor;

    f32x4 acc[6][4][2];
#pragma unroll
    for (int g = 0; g < 6; ++g)
#pragma unroll
        for (int mi = 0; mi < 4; ++mi)
#pragma unroll
            for (int ni = 0; ni < 2; ++ni)
                acc[g][mi][ni] = f32x4{0.f, 0.f, 0.f, 0.f};

    // 5 gload_lds per wave per stage (2 A + 3 B) -> vmcnt counts in units of 5
    auto stage = [&](int ksn, unsigned bufOff) {
#pragma unroll
        for (int i = 0; i < 2; ++i) {
            const unsigned short* src = (ksn < 16) ? (fb + aOff[i] + ksn * 32)
                                                   : (hb + hOff[i] + (ksn - 16) * 32);
            gload16(src, sm + bufOff + i * 8192 + ldsW);
        }
#pragma unroll
        for (int i = 0; i < 3; ++i)
            gload16(wcat + bOff[i] + ksn * 32, sm + bufOff + 16384 + i * 8192 + ldsW);
    };

    // ---- prologue: fill buffers 0 and 1 ----
    stage(0, 0u);
    stage(1, LDS_BUF);
    unsigned curOff = 0, stOff = 2 * LDS_BUF;

    for (int ks = 0; ks < nks; ++ks) {
        // counted wait: stage(ks) landed; stage(ks+1)'s 5 loads stay in flight
        if (ks + 1 < nks) asm volatile("s_waitcnt vmcnt(5)" ::: "memory");
        else              asm volatile("s_waitcnt vmcnt(0)" ::: "memory");
        __builtin_amdgcn_s_barrier();
        __builtin_amdgcn_sched_barrier(0);
        if (ks + 2 < nks) stage(ks + 2, stOff);   // WAR-safe: buf read 2 steps ago

        const unsigned char* cur = sm + curOff;
        short8 a[4];
#pragma unroll
        for (int mi = 0; mi < 4; ++mi)
            a[mi] = *(const short8*)(cur + aBase + mi * 1024);
        __builtin_amdgcn_s_setprio(1);
#pragma unroll
        for (int g = 0; g < 6; ++g) {
            if (g == 5 && ks >= 16) break;        // px strip: B is zero for K>=512
            short8 b0 = *(const short8*)(cur + bBase + g * 4096);
            short8 b1 = *(const short8*)(cur + bBase + g * 4096 + 1024);
#pragma unroll
            for (int mi = 0; mi < 4; ++mi) {
                acc[g][mi][0] = __builtin_amdgcn_mfma_f32_16x16x32_bf16(a[mi], b0, acc[g][mi][0], 0, 0, 0);
                acc[g][mi][1] = __builtin_amdgcn_mfma_f32_16x16x32_bf16(a[mi], b1, acc[g][mi][1], 0, 0, 0);
            }
        }
        __builtin_amdgcn_s_setprio(0);
        curOff += LDS_BUF; if (curOff == 3 * LDS_BUF) curOff = 0;
        stOff  += LDS_BUF; if (stOff  == 3 * LDS_BUF) stOff  = 0;
    }

    // ---- epilogue: gates + highway. C/D layout: col=lane&15, row=q4*4+q
    const int colb = j0 + wc * 32 + (lane & 15);
#pragma unroll
    for (int ni = 0; ni < 2; ++ni) {
        const int j = colb + ni * 16;
        const float Bi = bx[j]        + bh[j];
        const float Bo = bx[j + 512]  + bh[j + 512];
        const float Bf = bx[j + 1024] + bh[j + 1024];
        const float Bu = bx[j + 1536] + bh[j + 1536];
        const float Br = bx[j + 2048] + bh[j + 2048];
        const float Bp = bp[j];
#pragma unroll
        for (int mi = 0; mi < 4; ++mi) {
            const int rowb = wr * 64 + mi * 16 + (q4 << 2);
#pragma unroll
            for (int q = 0; q < 4; ++q) {
                int n = nbase + rowb + q;
                if (n >= e) continue;
                float gi = sigm(acc[0][mi][ni][q] + Bi);
                float go = sigm(acc[1][mi][ni][q] + Bo);
                float gf = sigm(acc[2][mi][ni][q] + Bf);
                float gu = tanh_fast(acc[3][mi][ni][q] + Bu);
                float gr = sigm(acc[4][mi][ni][q] + Br);
                float pp = acc[5][mi][ni][q] + Bp;
                float pc = (level > 0) ? c_all[(size_t)((n - 1) >> 3) * 512 + j] : 0.0f;
                float cg = gi * gu + gf * pc;
                float hh = go * tanh_fast(cg);
                float hf = gr * hh + (1.0f - gr) * pp;
                size_t o = (size_t)n * 512 + j;
                c_all[o] = cg;
                out[o] = hf;
                hb[o] = f2b(hf);
            }
        }
    }
}

// ---------- host ----------
extern "C" void kernel_launch(void* const* d_in, const int* in_sizes, int n_in,
                              void* d_out, int out_size, void* d_ws, size_t ws_size,
                              hipStream_t stream) {
    const float* feats = (const float*)d_in[0];
    const float* Wx = (const float*)d_in[1];
    const float* bx = (const float*)d_in[2];
    const float* Wh = (const float*)d_in[3];
    const float* bh = (const float*)d_in[4];
    const float* Wp = (const float*)d_in[5];
    const float* bp = (const float*)d_in[6];
    float* out = (float*)d_out;

    const int N = in_sizes[0] / 512;

    unsigned short* fb = (unsigned short*)d_ws;                 // N*512 bf16
    unsigned short* wcat = fb + (size_t)N * 512;                // 3072*1024 bf16
    unsigned short* hb = wcat + (size_t)3072 * 1024;            // N*512 bf16
    float* c_all = (float*)(hb + (size_t)N * 512);              // N*512 f32

    const int nf4 = N * 512 / 4;
    const int nw4 = 3072 * 1024 / 4;
    convert_kernel<<<dim3(2048), dim3(256), 0, stream>>>(feats, Wx, Wh, Wp, fb, wcat, nf4, nw4);

    int bounds[16];
    bounds[0] = 0;
    long cnt = 1;
    int nl = 0;
    while (bounds[nl] < N) {
        long nxt = (long)bounds[nl] + cnt;
        if (nxt > N) nxt = N;
        bounds[nl + 1] = (int)nxt;
        nl++;
        cnt *= 8;
    }

    for (int l = 0; l < nl; ++l) {
        int s = bounds[l], e = bounds[l + 1];
        int rows = e - s;
        int nks = (l > 0) ? 32 : 16;
        dim3 grid((rows + 255) / 256, 8);
        level_kernel<<<grid, dim3(512), 0, stream>>>(fb, wcat, hb, bx, bh, bp, c_all, out, s, e, l, nks);
    }
}